// Round 6
// baseline (492.437 us; speedup 1.0000x reference)
//
#include <hip/hip_runtime.h>
#include <hip/hip_bf16.h>
#include <cstdint>
#include <cstddef>

typedef unsigned short u16;
typedef __attribute__((ext_vector_type(8))) short short8;
typedef __attribute__((ext_vector_type(4))) float f32x4;

// ---------- helpers ----------
__device__ __forceinline__ float b2f(u16 h){ union{unsigned u; float f;} c; c.u = ((unsigned)h)<<16; return c.f; }
__device__ __forceinline__ u16 f2b(float f){ union{float f; unsigned u;} c; c.f = f; unsigned u = c.u; return (u16)((u + 0x7fffu + ((u>>16)&1u)) >> 16); }
__device__ __forceinline__ float gelu_f(float x){
  float x3 = x*x*x;
  return 0.5f*x*(1.f + tanhf(0.7978845608028654f*(x + 0.044715f*x3)));
}
__device__ __forceinline__ void gload_lds16(const void* g, void* l){
  __builtin_amdgcn_global_load_lds((const __attribute__((address_space(1))) void*)g,
                                   (__attribute__((address_space(3))) void*)l, 16, 0, 0);
}

// ---------- LayerNorm: one block per token, float4 + wave reduce ----------
__global__ __launch_bounds__(256) void k_ln(const float* __restrict__ x, const float* __restrict__ w,
    const float* __restrict__ b, float* __restrict__ xn)
{
  int t = blockIdx.x, tid = threadIdx.x;
  float4 v = ((const float4*)(x + (size_t)t*1024))[tid];
  float s = v.x+v.y+v.z+v.w;
  #pragma unroll
  for (int o=32;o;o>>=1) s += __shfl_xor(s,o,64);
  __shared__ float r1[4], r2[4];
  if ((tid&63)==0) r1[tid>>6] = s;
  __syncthreads();
  float mu = (r1[0]+r1[1]+r1[2]+r1[3]) * (1.f/1024.f);
  float4 c = {v.x-mu, v.y-mu, v.z-mu, v.w-mu};
  float q = c.x*c.x+c.y*c.y+c.z*c.z+c.w*c.w;
  #pragma unroll
  for (int o=32;o;o>>=1) q += __shfl_xor(q,o,64);
  if ((tid&63)==0) r2[tid>>6] = q;
  __syncthreads();
  float inv = rsqrtf((r2[0]+r2[1]+r2[2]+r2[3])*(1.f/1024.f) + 1e-5f);
  float4 wv = ((const float4*)w)[tid];
  float4 bv = ((const float4*)b)[tid];
  float4 o4 = {c.x*inv*wv.x+bv.x, c.y*inv*wv.y+bv.y, c.z*inv*wv.z+bv.z, c.w*inv*wv.w+bv.w};
  ((float4*)(xn + (size_t)t*1024))[tid] = o4;
}

// ---------- transpose + fp32->bf16 convert: src[R][C] -> dst[C][R] ----------
__global__ __launch_bounds__(256) void k_tcvt(const float* __restrict__ src, u16* __restrict__ dst, int R, int C)
{
  __shared__ float tile[32][33];
  int c0 = blockIdx.x*32, r0 = blockIdx.y*32;
  int lc = threadIdx.x & 31, lr = threadIdx.x >> 5;
  #pragma unroll
  for (int rr=0; rr<4; rr++) tile[lr + rr*8][lc] = src[(size_t)(r0 + lr + rr*8)*C + c0 + lc];
  __syncthreads();
  #pragma unroll
  for (int rr=0; rr<4; rr++) dst[(size_t)(c0 + lr + rr*8)*R + r0 + lc] = f2b(tile[lc][lr + rr*8]);
}

// ---------- pack qkv bias ----------
__global__ __launch_bounds__(256) void k_bpack(const float* __restrict__ bq, const float* __restrict__ bk,
    const float* __restrict__ bv, float* __restrict__ o)
{
  int i = blockIdx.x*256 + threadIdx.x;
  o[i] = (i < 1024) ? bq[i] : ((i < 2048) ? bk[i-1024] : bv[i-2048]);
}

// ---------- router hi/lo split: A_packed[4096][3072] = [Ah|Ah|Al] ----------
__global__ __launch_bounds__(256) void k_splitA(const float* __restrict__ xn, u16* __restrict__ ap)
{
  int id = blockIdx.x*256 + threadIdx.x;      // 4096*1024
  int t = id >> 10, k = id & 1023;
  float x = xn[id];
  u16 hi = f2b(x);
  u16 lo = f2b(x - b2f(hi));
  u16* row = ap + (size_t)t*3072;
  row[k] = hi; row[1024+k] = hi; row[2048+k] = lo;
}

// ---------- router w1 transpose + split: B_packed[512][3072] = [Bh|Bl|Bh] ----------
__global__ __launch_bounds__(256) void k_splitB(const float* __restrict__ w1, u16* __restrict__ bp)
{
  __shared__ float tile[32][33];
  int n0 = blockIdx.x*32, k0 = blockIdx.y*32;
  int lc = threadIdx.x & 31, lr = threadIdx.x >> 5;
  #pragma unroll
  for (int rr=0; rr<4; rr++) tile[lr+rr*8][lc] = w1[(size_t)(k0+lr+rr*8)*512 + n0+lc];
  __syncthreads();
  #pragma unroll
  for (int rr=0; rr<4; rr++){
    int n = n0 + lr + rr*8, k = k0 + lc;
    float x = tile[lc][lr+rr*8];
    u16 hi = f2b(x);
    u16 lo = f2b(x - b2f(hi));
    u16* row = bp + (size_t)n*3072;
    row[k] = hi; row[1024+k] = lo; row[2048+k] = hi;
  }
}

// ---------- router score ----------
__global__ __launch_bounds__(256) void k_score(const float* __restrict__ h, const float* __restrict__ w2,
    const float* __restrict__ b2, float* __restrict__ scores)
{
  int tok = blockIdx.x*4 + (threadIdx.x >> 6);
  int lane = threadIdx.x & 63;
  const float* hr = h + (size_t)tok*512;
  float s = 0.f;
  #pragma unroll
  for (int i=0;i<8;i++) s += hr[lane + i*64] * w2[lane + i*64];
  #pragma unroll
  for (int o=32;o;o>>=1) s += __shfl_xor(s, o, 64);
  if (lane==0) scores[tok] = s + b2[0];
}

// ---------- exact top-k (rank-based, jax tie semantics) + compaction ----------
__global__ __launch_bounds__(1024) void k_topk(const float* __restrict__ scores, int* __restrict__ aidx, int* __restrict__ sidx)
{
  int b = blockIdx.x, tid = threadIdx.x;
  __shared__ float s[1024];
  __shared__ int pf[1024];
  s[tid] = scores[b*1024 + tid];
  __syncthreads();
  float my = s[tid];
  int cnt = 0;
  for (int j=0;j<1024;j++){ float sj = s[j]; cnt += (sj > my) || (sj == my && j < tid); }
  int isa = (cnt < 256) ? 1 : 0;
  pf[tid] = isa; __syncthreads();
  for (int o=1;o<1024;o<<=1){
    int add = (tid >= o) ? pf[tid-o] : 0;
    __syncthreads();
    pf[tid] += add;
    __syncthreads();
  }
  int excl = pf[tid] - isa;
  if (isa) aidx[b*256 + excl] = tid;
  else     sidx[b*768 + (tid - excl)] = tid;
}

// ---------- gather compacted rows, fp32 -> bf16 (16B loads / 8B stores) ----------
__global__ __launch_bounds__(256) void k_gather(const float* __restrict__ xn, const int* __restrict__ aidx,
    const int* __restrict__ sidx, u16* __restrict__ xat, u16* __restrict__ xst)
{
  int id = blockIdx.x;
  int b = id >> 10, s = id & 1023;
  int src; u16* dst;
  if (s < 256) { src = aidx[b*256 + s]; dst = xat + (size_t)(b*256 + s)*1024; }
  else { int ss = s - 256; src = sidx[b*768 + ss]; dst = xst + (size_t)(b*768 + ss)*1024; }
  const float4* sp = (const float4*)(xn + ((size_t)b*1024 + src)*1024);
  int tid = threadIdx.x;
  float4 vv = sp[tid];
  union { u16 u[4]; uint2 d; } pk;
  pk.u[0]=f2b(vv.x); pk.u[1]=f2b(vv.y); pk.u[2]=f2b(vv.z); pk.u[3]=f2b(vv.w);
  ((uint2*)dst)[tid] = pk.d;
}

// ---------- MFMA bf16 GEMM, 2-phase pipelined, swizzled LDS ----------
// C[M][N] = A[M][K] @ Bt[N][K]^T (+bias, +act). Output routing: col<split ->
// fp32 outf[row*split+col]; col>=split -> bf16 outb[row*(N-split)+(col-split)].
// Split-K via gridDim.z. act: 1=softplus, 2=gelu.
template<int BM, int BN>
__global__ __launch_bounds__(256) void k_mfma(const u16* __restrict__ A, int lda,
    const u16* __restrict__ Bt, int ldb, const float* __restrict__ bias,
    float* __restrict__ outf, u16* __restrict__ outb, int M, int N, int K,
    int act, int split)
{
  constexpr int WTM = BM/2, WTN = BN/2;
  constexpr int MI = WTM/16, NJ = WTN/16;
  __shared__ u16 lA[2][BM*32];
  __shared__ u16 lB[2][BN*32];
  const int tid = threadIdx.x;
  const int lane = tid & 63;
  const int wv = tid >> 6;
  const int wm = wv >> 1, wn = wv & 1;
  const int tm = blockIdx.x * BM, tn = blockIdx.y * BN;
  const int r0 = lane & 15;
  const int kg = lane >> 4;

  const int ksl = K / gridDim.z;
  const int kbeg = blockIdx.z * ksl;
  if (gridDim.z > 1) outf += (size_t)blockIdx.z * ((size_t)M * N);

  auto stage = [&](int buf, int kt){
    for (int c = tid; c < BM*4; c += 256) {
      int row = c >> 2, j = c & 3;
      int jj = j ^ ((row >> 1) & 3);
      gload_lds16(&A[(size_t)(tm + row)*lda + kt + jj*8], &lA[buf][c*8]);
    }
    for (int c = tid; c < BN*4; c += 256) {
      int row = c >> 2, j = c & 3;
      int jj = j ^ ((row >> 1) & 3);
      gload_lds16(&Bt[(size_t)(tn + row)*ldb + kt + jj*8], &lB[buf][c*8]);
    }
  };

  f32x4 acc[MI][NJ];
  #pragma unroll
  for (int i=0;i<MI;i++)
    #pragma unroll
    for (int j=0;j<NJ;j++) acc[i][j] = (f32x4){0.f,0.f,0.f,0.f};

  stage(0, kbeg);
  __syncthreads();
  const int nk = ksl / 32;
  int cur = 0;
  for (int t = 0; t < nk; t++) {
    if (t + 1 < nk) stage(cur ^ 1, kbeg + (t+1)*32);
    short8 av[MI], bvv[NJ];
    #pragma unroll
    for (int i=0;i<MI;i++){
      int row = wm*WTM + i*16 + r0;
      av[i] = *(const short8*)&lA[cur][row*32 + ((kg ^ ((row>>1)&3))<<3)];
    }
    #pragma unroll
    for (int j=0;j<NJ;j++){
      int row = wn*WTN + j*16 + r0;
      bvv[j] = *(const short8*)&lB[cur][row*32 + ((kg ^ ((row>>1)&3))<<3)];
    }
    #pragma unroll
    for (int i=0;i<MI;i++)
      #pragma unroll
      for (int j=0;j<NJ;j++)
        acc[i][j] = __builtin_amdgcn_mfma_f32_16x16x32_bf16(av[i], bvv[j], acc[i][j], 0, 0, 0);
    __syncthreads();
    cur ^= 1;
  }

  const int rr = kg * 4;
  #pragma unroll
  for (int i=0;i<MI;i++){
    #pragma unroll
    for (int j=0;j<NJ;j++){
      #pragma unroll
      for (int r=0;r<4;r++){
        int row = tm + wm*WTM + i*16 + rr + r;
        int col = tn + wn*WTN + j*16 + r0;
        float v = acc[i][j][r];
        if (bias) v += bias[col];
        if (act == 1) v = (v > 15.f) ? v : log1pf(__expf(v));
        else if (act == 2) v = gelu_f(v);
        if (col < split) outf[(size_t)row*split + col] = v;
        else             outb[(size_t)row*(N-split) + (col-split)] = f2b(v);
      }
    }
  }
}

// ---------- split-K partial reduction for x-proj (+ dtp bf16 extract) ----------
__global__ __launch_bounds__(256) void k_psum(const float* __restrict__ p, float* __restrict__ o,
    u16* __restrict__ dtpb)
{
  int i = blockIdx.x*256 + threadIdx.x;   // 3072*96 = 294912
  float v = p[i] + p[i+294912] + p[i+589824] + p[i+884736];
  o[i] = v;
  int tok = i / 96, col = i - tok*96;
  if (col < 64) dtpb[tok*64 + col] = f2b(v);
}

// ---------- MFMA attention core (qkv packed [tok][3072]: q|k|v) ----------
__global__ __launch_bounds__(256) void k_attn2(const u16* __restrict__ qkv, u16* __restrict__ ob)
{
  __shared__ u16 lKP[16384];
  __shared__ u16 lVt[16384];
  char* KP = (char*)lKP;
  char* VT = (char*)lVt;
  const int tid = threadIdx.x;
  const int lane = tid & 63;
  const int w = tid >> 6;
  const int bx = blockIdx.x;
  const int b = bx >> 6, h = (bx >> 2) & 15, ch = bx & 3;

  const u16* kbase = qkv + (size_t)(b*256)*3072 + 1024 + h*64;
  const u16* vbase = qkv + (size_t)(b*256)*3072 + 2048 + h*64;

  {
    int rr = tid >> 3;
    int c8 = (tid & 7) * 8;
    for (int i = 0; i < 8; i++) {
      int row = i*32 + rr;
      int4 kv = *(const int4*)&kbase[(size_t)row*3072 + c8];
      int koff = row*128 + c8*2;
      *(int4*)(KP + (koff ^ ((row & 7) << 4))) = kv;
      int4 vv = *(const int4*)&vbase[(size_t)row*3072 + c8];
      union { int4 q; u16 u[8]; } vu; vu.q = vv;
      #pragma unroll
      for (int jj = 0; jj < 8; jj++) {
        int j = (jj + rr) & 7;
        int d = c8 + j;
        int voff = d*512 + row*2;
        *(u16*)(VT + (voff ^ ((d & 7) << 4))) = vu.u[j];
      }
    }
  }

  const int r0 = lane & 15;
  const int kg = lane >> 4;
  const int qrow = ch*64 + w*16 + r0;
  const u16* qp = qkv + (size_t)(b*256 + qrow)*3072 + h*64 + kg*8;
  short8 qf0 = *(const short8*)(qp);
  short8 qf1 = *(const short8*)(qp + 32);

  __syncthreads();

  f32x4 acc[16];
  #pragma unroll
  for (int t = 0; t < 16; t++) acc[t] = (f32x4){0.f,0.f,0.f,0.f};
  #pragma unroll
  for (int t = 0; t < 16; t++) {
    int row = t*16 + r0;
    int base = row*128 + kg*16;
    short8 kf0 = *(const short8*)(KP + ((base     ) ^ ((row & 7) << 4)));
    short8 kf1 = *(const short8*)(KP + ((base + 64) ^ ((row & 7) << 4)));
    acc[t] = __builtin_amdgcn_mfma_f32_16x16x32_bf16(qf0, kf0, acc[t], 0, 0, 0);
    acc[t] = __builtin_amdgcn_mfma_f32_16x16x32_bf16(qf1, kf1, acc[t], 0, 0, 0);
  }

  #pragma unroll
  for (int t = 0; t < 16; t++) acc[t] = acc[t] * 0.125f;
  float lsum[4];
  #pragma unroll
  for (int r = 0; r < 4; r++) {
    float mx = -1e30f;
    #pragma unroll
    for (int t = 0; t < 16; t++) mx = fmaxf(mx, acc[t][r]);
    #pragma unroll
    for (int o = 1; o < 16; o <<= 1) mx = fmaxf(mx, __shfl_xor(mx, o, 64));
    float s = 0.f;
    #pragma unroll
    for (int t = 0; t < 16; t++) { float p = __expf(acc[t][r] - mx); acc[t][r] = p; s += p; }
    #pragma unroll
    for (int o = 1; o < 16; o <<= 1) s += __shfl_xor(s, o, 64);
    lsum[r] = s;
  }

  __syncthreads();
  char* PW = KP + w*8192;
  #pragma unroll
  for (int t = 0; t < 16; t++) {
    int col = t*16 + r0;
    #pragma unroll
    for (int r = 0; r < 4; r++) {
      int row = kg*4 + r;
      int off = row*512 + col*2;
      *(u16*)(PW + (off ^ ((row & 7) << 4))) = f2b(acc[t][r]);
    }
  }

  f32x4 oacc[4];
  #pragma unroll
  for (int dt = 0; dt < 4; dt++) oacc[dt] = (f32x4){0.f,0.f,0.f,0.f};
  #pragma unroll
  for (int kc = 0; kc < 8; kc++) {
    int pbase = r0*512 + kc*64 + kg*16;
    short8 pf = *(const short8*)(PW + (pbase ^ ((r0 & 7) << 4)));
    #pragma unroll
    for (int dt = 0; dt < 4; dt++) {
      int vrow = dt*16 + r0;
      int vb2 = vrow*512 + kc*64 + kg*16;
      short8 vf = *(const short8*)(VT + (vb2 ^ ((vrow & 7) << 4)));
      oacc[dt] = __builtin_amdgcn_mfma_f32_16x16x32_bf16(pf, vf, oacc[dt], 0, 0, 0);
    }
  }

  u16* op = ob + (size_t)(b*256 + ch*64 + w*16)*1024 + h*64;
  #pragma unroll
  for (int dt = 0; dt < 4; dt++) {
    #pragma unroll
    for (int r = 0; r < 4; r++) {
      int row = kg*4 + r;
      float v = oacc[dt][r] / lsum[r];
      op[(size_t)row*1024 + dt*16 + r0] = f2b(v);
    }
  }
}

// ---------- causal depthwise conv (DC=4) + SiLU ----------
__global__ __launch_bounds__(256) void k_conv(const float* __restrict__ xi, const float* __restrict__ cw,
    const float* __restrict__ cb, float* __restrict__ xc, u16* __restrict__ xcb)
{
  size_t idx = (size_t)blockIdx.x*256 + threadIdx.x;
  int d = (int)(idx & 2047);
  size_t bt = idx >> 11;
  int t = (int)(bt % 768);
  float acc = cb[d];
  const float* p = xi + idx;
  float w0=cw[d*4+0], w1=cw[d*4+1], w2=cw[d*4+2], w3=cw[d*4+3];
  acc += w3 * p[0];
  if (t >= 1) acc += w2 * p[-2048];
  if (t >= 2) acc += w1 * p[-4096];
  if (t >= 3) acc += w0 * p[-6144];
  float sv = acc / (1.f + __expf(-acc));
  xc[idx]  = sv;
  xcb[idx] = f2b(sv);
}

// ================= chunked parallel selective scan =================
__global__ __launch_bounds__(256) void k_scan1(const float* __restrict__ delta, const float* __restrict__ xc,
    const float* __restrict__ proj, const float* __restrict__ A_log, float* __restrict__ cs)
{
  int bid = blockIdx.x;
  int db = bid & 7;
  int c  = (bid >> 3) & 15;
  int b  = bid >> 7;
  int d  = db*256 + threadIdx.x;
  float Ar[16];
  #pragma unroll
  for (int s=0;s<16;s++) Ar[s] = -__expf(A_log[d*16+s]);
  float ap[16], hc[16];
  #pragma unroll
  for (int s=0;s<16;s++){ ap[s]=1.f; hc[s]=0.f; }
  size_t row0 = (size_t)b*768 + c*48;
  for (int t=0;t<48;t++){
    size_t row = row0 + t;
    float dl = delta[row*2048 + d];
    float xv = xc[row*2048 + d];
    float du = dl*xv;
    const float4* bp = (const float4*)&proj[row*96 + 64];
    float4 b0 = bp[0], b1 = bp[1], b2 = bp[2], b3 = bp[3];
    float Bc[16] = {b0.x,b0.y,b0.z,b0.w,b1.x,b1.y,b1.z,b1.w,
                    b2.x,b2.y,b2.z,b2.w,b3.x,b3.y,b3.z,b3.w};
    #pragma unroll
    for (int s=0;s<16;s++){
      float dA = __expf(dl*Ar[s]);
      ap[s] *= dA;
      hc[s] = dA*hc[s] + du*Bc[s];
    }
  }
  size_t base = ((size_t)(b*16 + c)*32)*2048 + d;
  #pragma unroll
  for (int s=0;s<16;s++){
    cs[base + (size_t)s*2048]      = ap[s];
    cs[base + (size_t)(16+s)*2048] = hc[s];
  }
}

__global__ __launch_bounds__(256) void k_scan2(float* __restrict__ cs)
{
  int bid = blockIdx.x;
  int db = bid & 7;
  int s  = (bid >> 3) & 15;
  int b  = bid >> 7;
  int d  = db*256 + threadIdx.x;
  float h = 0.f;
  for (int c=0;c<16;c++){
    size_t base = ((size_t)(b*16 + c)*32)*2048 + d;
    float ap = cs[base + (size_t)s*2048];
    float hc = cs[base + (size_t)(16+s)*2048];
    cs[base + (size_t)(16+s)*2048] = h;
    h = ap*h + hc;
  }
}

__global__ __launch_bounds__(256) void k_scan3(const float* __restrict__ delta, const float* __restrict__ xc,
    const float* __restrict__ proj, const float* __restrict__ cs, const u16* __restrict__ zb,
    const float* __restrict__ A_log, const float* __restrict__ Dp, u16* __restrict__ yb)
{
  int bid = blockIdx.x;
  int db = bid & 7;
  int c  = (bid >> 3) & 15;
  int b  = bid >> 7;
  int d  = db*256 + threadIdx.x;
  float Ar[16];
  #pragma unroll
  for (int s=0;s<16;s++) Ar[s] = -__expf(A_log[d*16+s]);
  float dpv = Dp[d];
  float h[16];
  size_t base = ((size_t)(b*16 + c)*32)*2048 + d;
  #pragma unroll
  for (int s=0;s<16;s++) h[s] = cs[base + (size_t)(16+s)*2048];
  size_t row0 = (size_t)b*768 + c*48;
  for (int t=0;t<48;t++){
    size_t row = row0 + t;
    float dl = delta[row*2048 + d];
    float xv = xc[row*2048 + d];
    float du = dl*xv;
    const float4* bp = (const float4*)&proj[row*96 + 64];
    float4 b0 = bp[0], b1 = bp[1], b2 = bp[2], b3 = bp[3];
    const float4* cp = (const float4*)&proj[row*96 + 80];
    float4 c0 = cp[0], c1 = cp[1], c2 = cp[2], c3 = cp[3];
    float Bc[16] = {b0.x,b0.y,b0.z,b0.w,b1.x,b1.y,b1.z,b1.w,
                    b2.x,b2.y,b2.z,b2.w,b3.x,b3.y,b3.z,b3.w};
    float Cc[16] = {c0.x,c0.y,c0.z,c0.w,c1.x,c1.y,c1.z,c1.w,
                    c2.x,c2.y,c2.z,c2.w,c3.x,c3.y,c3.z,c3.w};
    float y = 0.f;
    #pragma unroll
    for (int s=0;s<16;s++){
      float dA = __expf(dl*Ar[s]);
      h[s] = dA*h[s] + du*Bc[s];
      y += h[s]*Cc[s];
    }
    y += xv*dpv;
    float z = b2f(zb[row*2048 + d]);
    float g = z / (1.f + __expf(-z));
    yb[row*2048 + d] = f2b(y*g);
  }
}

// ---------- scatter (float4) ----------
__global__ __launch_bounds__(256) void k_scat(const float* __restrict__ x, const int* __restrict__ idxarr,
    const float* __restrict__ dlt, float* __restrict__ out, int per_b)
{
  int id = blockIdx.x;
  int b = id / per_b;
  int t = idxarr[id];
  const float4* xp = (const float4*)(x + ((size_t)b*1024 + t)*1024);
  const float4* dp = (const float4*)(dlt + (size_t)id*1024);
  float4* op = (float4*)(out + ((size_t)b*1024 + t)*1024);
  int tid = threadIdx.x;
  float4 a = xp[tid], d = dp[tid];
  op[tid] = (float4){a.x+d.x, a.y+d.y, a.z+d.z, a.w+d.w};
}

// ------------------------------------------------------------------
extern "C" void kernel_launch(void* const* d_in, const int* in_sizes, int n_in,
                              void* d_out, int out_size, void* d_ws, size_t ws_size,
                              hipStream_t stream)
{
  const float* x      = (const float*)d_in[0];
  const float* ln_w   = (const float*)d_in[1];
  const float* ln_b   = (const float*)d_in[2];
  const float* r_w1   = (const float*)d_in[3];
  const float* r_b1   = (const float*)d_in[4];
  const float* r_w2   = (const float*)d_in[5];
  const float* r_b2   = (const float*)d_in[6];
  const float* Wq     = (const float*)d_in[7];
  const float* bq     = (const float*)d_in[8];
  const float* Wk     = (const float*)d_in[9];
  const float* bk     = (const float*)d_in[10];
  const float* Wv     = (const float*)d_in[11];
  const float* bv     = (const float*)d_in[12];
  const float* Wo     = (const float*)d_in[13];
  const float* bo     = (const float*)d_in[14];
  const float* in_w   = (const float*)d_in[15];
  const float* conv_w = (const float*)d_in[16];
  const float* conv_b = (const float*)d_in[17];
  const float* xproj_w= (const float*)d_in[18];
  const float* dt_w   = (const float*)d_in[19];
  const float* dt_b   = (const float*)d_in[20];
  const float* A_log  = (const float*)d_in[21];
  const float* Dp     = (const float*)d_in[22];
  const float* out_w  = (const float*)d_in[23];
  float* out = (float*)d_out;

  uint8_t* ws = (uint8_t*)d_ws;
  size_t off = 0;
  auto alloc = [&](size_t bytes)->uint8_t*{
    uint8_t* p = ws + off;
    off += (bytes + 255) & ~(size_t)255;
    return p;
  };

  float* xn    = (float*)alloc(4096ull*1024*4);
  u16*   wqt   = (u16*)  alloc(1024ull*1024*2);   // wqt/wkt/wvt contiguous => [3072][1024]
  u16*   wkt   = (u16*)  alloc(1024ull*1024*2);
  u16*   wvt   = (u16*)  alloc(1024ull*1024*2);
  u16*   wot   = (u16*)  alloc(1024ull*1024*2);
  u16*   inwt  = (u16*)  alloc(4096ull*1024*2);
  u16*   outwt = (u16*)  alloc(1024ull*2048*2);
  u16*   xpwt  = (u16*)  alloc(96ull*2048*2);
  u16*   dtwt  = (u16*)  alloc(2048ull*64*2);
  u16*   r1pk  = (u16*)  alloc(512ull*3072*2);    // router B_packed
  float* scores= (float*)alloc(4096*4);
  int*   aidx  = (int*)  alloc(1024*4);
  int*   sidx  = (int*)  alloc(3072*4);
  u16*   xat   = (u16*)  alloc(1024ull*1024*2);
  u16*   xst   = (u16*)  alloc(3072ull*1024*2);
  float* qkvb  = (float*)alloc(3072*4);

  // xn region reuse: split-K partials (before scan), then scan chunk-state (16MB)
  float* s_projp = xn;
  float* cs = xn;

  uint8_t* arena = ws + off;
  // phase: router
  float* h  = (float*)arena;                                  // 8 MB
  u16*   apk = (u16*)(arena + 8388608);                       // A_packed 4096*3072*2 = 25.2 MB
  // phase: attention
  u16*   qkvbuf = (u16*)(arena);                              // 6 MB
  u16*   obuf   = (u16*)(arena + 6291456);                    // 2 MB
  float* adelta = (float*)(arena + 8388608);                  // 4 MB
  // phase: ssm
  float* s_xi   = (float*)(arena);                            // 25165824 (reused as delta)
  u16*   s_zb   = (u16*)(arena + 25165824);                   // 12582912 (reused as ssm_delta fp32)
  float* s_xc   = (float*)(arena + 37748736);                 // 25165824
  u16*   s_xcb  = (u16*)(arena + 62914560);                   // 12582912 (reused as y bf16)
  float* s_proj = (float*)(arena + 75497472);                 // 1179648
  u16*   s_dtpb = (u16*)(arena + 76677120);                   // 393216
  float* s_delta  = s_xi;
  u16*   s_yb     = s_xcb;
  float* s_sdelta = (float*)s_zb;

  // 1) LayerNorm
  hipLaunchKernelGGL(k_ln, dim3(4096), dim3(256), 0, stream, x, ln_w, ln_b, xn);
  // 2) weight convert+transpose to bf16 [N][K] + bias pack + router splits
  hipLaunchKernelGGL(k_tcvt, dim3(32,32),  dim3(256), 0, stream, Wq,     wqt,   1024, 1024);
  hipLaunchKernelGGL(k_tcvt, dim3(32,32),  dim3(256), 0, stream, Wk,     wkt,   1024, 1024);
  hipLaunchKernelGGL(k_tcvt, dim3(32,32),  dim3(256), 0, stream, Wv,     wvt,   1024, 1024);
  hipLaunchKernelGGL(k_tcvt, dim3(32,32),  dim3(256), 0, stream, Wo,     wot,   1024, 1024);
  hipLaunchKernelGGL(k_tcvt, dim3(128,32), dim3(256), 0, stream, in_w,   inwt,  1024, 4096);
  hipLaunchKernelGGL(k_tcvt, dim3(32,64),  dim3(256), 0, stream, out_w,  outwt, 2048, 1024);
  hipLaunchKernelGGL(k_tcvt, dim3(3,64),   dim3(256), 0, stream, xproj_w,xpwt,  2048, 96);
  hipLaunchKernelGGL(k_tcvt, dim3(64,2),   dim3(256), 0, stream, dt_w,   dtwt,  64,   2048);
  hipLaunchKernelGGL(k_bpack, dim3(12), dim3(256), 0, stream, bq, bk, bv, qkvb);
  hipLaunchKernelGGL(k_splitB, dim3(16,32), dim3(256), 0, stream, r_w1, r1pk);
  hipLaunchKernelGGL(k_splitA, dim3(16384), dim3(256), 0, stream, xn, apk);
  // 3) router GEMM via split-bf16 MFMA (K=3072), gelu fused
  hipLaunchKernelGGL((k_mfma<64,128>), dim3(64,4), dim3(256), 0, stream,
      apk, 3072, r1pk, 3072, r_b1, h, (u16*)nullptr, 4096, 512, 3072, 2, 512);
  // 4) scores
  hipLaunchKernelGGL(k_score, dim3(1024), dim3(256), 0, stream, h, r_w2, r_b2, scores);
  // 5) top-k + compaction
  hipLaunchKernelGGL(k_topk, dim3(4), dim3(1024), 0, stream, scores, aidx, sidx);
  // 6) gather
  hipLaunchKernelGGL(k_gather, dim3(4096), dim3(256), 0, stream, xn, aidx, sidx, xat, xst);
  // 7) QKV merged (N=3072, bf16 out)
  hipLaunchKernelGGL((k_mfma<64,128>), dim3(16,24), dim3(256), 0, stream,
      xat, 1024, wqt, 1024, qkvb, (float*)nullptr, qkvbuf, 1024, 3072, 1024, 0, 0);
  // 8) attention core (MFMA)
  hipLaunchKernelGGL(k_attn2, dim3(256), dim3(256), 0, stream, qkvbuf, obuf);
  // 9) Wo projection (fp32 out)
  hipLaunchKernelGGL((k_mfma<64,64>), dim3(16,16), dim3(256), 0, stream,
      obuf, 1024, wot, 1024, bo, adelta, (u16*)nullptr, 1024, 1024, 1024, 0, 1024);
  // 10) scatter attention tokens
  hipLaunchKernelGGL(k_scat, dim3(1024), dim3(256), 0, stream, x, aidx, adelta, out, 256);
  // 11) SSM in-proj merged: xi (fp32, cols<2048) + z (bf16, cols>=2048)
  hipLaunchKernelGGL((k_mfma<128,128>), dim3(24,32), dim3(256), 0, stream,
      xst, 1024, inwt, 1024, (const float*)nullptr, s_xi, s_zb, 3072, 4096, 1024, 0, 2048);
  // 12) conv + silu
  hipLaunchKernelGGL(k_conv, dim3(24576), dim3(256), 0, stream, s_xi, conv_w, conv_b, s_xc, s_xcb);
  // 13) x-proj, split-K=4 (partials in xn region) + reduce (+dtp extract)
  hipLaunchKernelGGL((k_mfma<64,96>), dim3(48,1,4), dim3(256), 0, stream,
      s_xcb, 2048, xpwt, 2048, (const float*)nullptr, s_projp, (u16*)nullptr, 3072, 96, 2048, 0, 96);
  hipLaunchKernelGGL(k_psum, dim3(1152), dim3(256), 0, stream, s_projp, s_proj, s_dtpb);
  // 15) dt GEMM + softplus -> delta
  hipLaunchKernelGGL((k_mfma<128,128>), dim3(24,16), dim3(256), 0, stream,
      s_dtpb, 64, dtwt, 64, dt_b, s_delta, (u16*)nullptr, 3072, 2048, 64, 1, 2048);
  // 16) chunked parallel scan (3 phases) + gating -> y bf16
  hipLaunchKernelGGL(k_scan1, dim3(512), dim3(256), 0, stream, s_delta, s_xc, s_proj, A_log, cs);
  hipLaunchKernelGGL(k_scan2, dim3(512), dim3(256), 0, stream, cs);
  hipLaunchKernelGGL(k_scan3, dim3(512), dim3(256), 0, stream, s_delta, s_xc, s_proj, cs, s_zb, A_log, Dp, s_yb);
  // 17) out-proj
  hipLaunchKernelGGL((k_mfma<64,128>), dim3(48,8), dim3(256), 0, stream,
      s_yb, 2048, outwt, 2048, (const float*)nullptr, s_sdelta, (u16*)nullptr, 3072, 1024, 2048, 0, 1024);
  // 18) scatter ssm tokens
  hipLaunchKernelGGL(k_scat, dim3(3072), dim3(256), 0, stream, x, sidx, s_sdelta, out, 768);
}

// Round 8
// 436.036 us; speedup vs baseline: 1.1294x; 1.1294x over previous
//
#include <hip/hip_runtime.h>
#include <hip/hip_bf16.h>
#include <cstdint>
#include <cstddef>

typedef unsigned short u16;
typedef __attribute__((ext_vector_type(8))) short short8;
typedef __attribute__((ext_vector_type(4))) float f32x4;

// ---------- helpers ----------
__device__ __forceinline__ float b2f(u16 h){ union{unsigned u; float f;} c; c.u = ((unsigned)h)<<16; return c.f; }
__device__ __forceinline__ u16 f2b(float f){ union{float f; unsigned u;} c; c.f = f; unsigned u = c.u; return (u16)((u + 0x7fffu + ((u>>16)&1u)) >> 16); }
__device__ __forceinline__ float gelu_f(float x){
  float x3 = x*x*x;
  return 0.5f*x*(1.f + tanhf(0.7978845608028654f*(x + 0.044715f*x3)));
}
__device__ __forceinline__ void gload_lds16(const void* g, void* l){
  __builtin_amdgcn_global_load_lds((const __attribute__((address_space(1))) void*)g,
                                   (__attribute__((address_space(3))) void*)l, 16, 0, 0);
}

// ---------- LayerNorm ----------
__global__ __launch_bounds__(256) void k_ln(const float* __restrict__ x, const float* __restrict__ w,
    const float* __restrict__ b, float* __restrict__ xn)
{
  int t = blockIdx.x, tid = threadIdx.x;
  float4 v = ((const float4*)(x + (size_t)t*1024))[tid];
  float s = v.x+v.y+v.z+v.w;
  #pragma unroll
  for (int o=32;o;o>>=1) s += __shfl_xor(s,o,64);
  __shared__ float r1[4], r2[4];
  if ((tid&63)==0) r1[tid>>6] = s;
  __syncthreads();
  float mu = (r1[0]+r1[1]+r1[2]+r1[3]) * (1.f/1024.f);
  float4 c = {v.x-mu, v.y-mu, v.z-mu, v.w-mu};
  float q = c.x*c.x+c.y*c.y+c.z*c.z+c.w*c.w;
  #pragma unroll
  for (int o=32;o;o>>=1) q += __shfl_xor(q,o,64);
  if ((tid&63)==0) r2[tid>>6] = q;
  __syncthreads();
  float inv = rsqrtf((r2[0]+r2[1]+r2[2]+r2[3])*(1.f/1024.f) + 1e-5f);
  float4 wv = ((const float4*)w)[tid];
  float4 bv = ((const float4*)b)[tid];
  float4 o4 = {c.x*inv*wv.x+bv.x, c.y*inv*wv.y+bv.y, c.z*inv*wv.z+bv.z, c.w*inv*wv.w+bv.w};
  ((float4*)(xn + (size_t)t*1024))[tid] = o4;
}

// ---------- transpose + fp32->bf16: src[R][C] -> dst[C][R] ----------
__global__ __launch_bounds__(256) void k_tcvt(const float* __restrict__ src, u16* __restrict__ dst, int R, int C)
{
  __shared__ float tile[32][33];
  int c0 = blockIdx.x*32, r0 = blockIdx.y*32;
  int lc = threadIdx.x & 31, lr = threadIdx.x >> 5;
  #pragma unroll
  for (int rr=0; rr<4; rr++) tile[lr + rr*8][lc] = src[(size_t)(r0 + lr + rr*8)*C + c0 + lc];
  __syncthreads();
  #pragma unroll
  for (int rr=0; rr<4; rr++) dst[(size_t)(c0 + lr + rr*8)*R + r0 + lc] = f2b(tile[lc][lr + rr*8]);
}

// ---------- pack qkv bias ----------
__global__ __launch_bounds__(256) void k_bpack(const float* __restrict__ bq, const float* __restrict__ bk,
    const float* __restrict__ bv, float* __restrict__ o)
{
  int i = blockIdx.x*256 + threadIdx.x;
  o[i] = (i < 1024) ? bq[i] : ((i < 2048) ? bk[i-1024] : bv[i-2048]);
}

// ---------- router hi/lo split: A_packed[4096][3072] = [Ah|Ah|Al] ----------
__global__ __launch_bounds__(256) void k_splitA(const float* __restrict__ xn, u16* __restrict__ ap)
{
  int t = blockIdx.x;
  int k4 = threadIdx.x*4;
  float4 v = *(const float4*)&xn[(size_t)t*1024 + k4];
  union{u16 u[4]; uint2 d;} hi, lo;
  float xs[4] = {v.x, v.y, v.z, v.w};
  #pragma unroll
  for (int e=0;e<4;e++){ u16 h = f2b(xs[e]); hi.u[e]=h; lo.u[e]=f2b(xs[e]-b2f(h)); }
  u16* row = ap + (size_t)t*3072;
  *(uint2*)&row[k4]      = hi.d;
  *(uint2*)&row[1024+k4] = hi.d;
  *(uint2*)&row[2048+k4] = lo.d;
}

// ---------- router w1 transpose + split: B_packed[512][3072] = [Bh|Bl|Bh] ----------
__global__ __launch_bounds__(256) void k_splitB(const float* __restrict__ w1, u16* __restrict__ bp)
{
  __shared__ float tile[32][33];
  int n0 = blockIdx.x*32, k0 = blockIdx.y*32;
  int lc = threadIdx.x & 31, lr = threadIdx.x >> 5;
  #pragma unroll
  for (int rr=0; rr<4; rr++) tile[lr+rr*8][lc] = w1[(size_t)(k0+lr+rr*8)*512 + n0+lc];
  __syncthreads();
  #pragma unroll
  for (int rr=0; rr<4; rr++){
    int n = n0 + lr + rr*8, k = k0 + lc;
    float x = tile[lc][lr+rr*8];
    u16 hi = f2b(x);
    u16 lo = f2b(x - b2f(hi));
    u16* row = bp + (size_t)n*3072;
    row[k] = hi; row[1024+k] = lo; row[2048+k] = hi;
  }
}

// ---------- score final reduce: scores = b2 + sum of 16 ps slices ----------
__global__ __launch_bounds__(256) void k_score3(const float* __restrict__ ps, const float* __restrict__ b2,
    float* __restrict__ scores)
{
  int i = blockIdx.x*256 + threadIdx.x;
  float s = b2[0];
  #pragma unroll
  for (int p=0;p<16;p++) s += ps[p*4096 + i];
  scores[i] = s;
}

// ---------- exact top-k (rank-based, jax tie semantics) + compaction ----------
__global__ __launch_bounds__(1024) void k_topk(const float* __restrict__ scores, int* __restrict__ aidx, int* __restrict__ sidx)
{
  int b = blockIdx.x, tid = threadIdx.x;
  __shared__ float s[1024];
  __shared__ int pf[1024];
  s[tid] = scores[b*1024 + tid];
  __syncthreads();
  float my = s[tid];
  int cnt = 0;
  for (int j=0;j<1024;j++){ float sj = s[j]; cnt += (sj > my) || (sj == my && j < tid); }
  int isa = (cnt < 256) ? 1 : 0;
  pf[tid] = isa; __syncthreads();
  for (int o=1;o<1024;o<<=1){
    int add = (tid >= o) ? pf[tid-o] : 0;
    __syncthreads();
    pf[tid] += add;
    __syncthreads();
  }
  int excl = pf[tid] - isa;
  if (isa) aidx[b*256 + excl] = tid;
  else     sidx[b*768 + (tid - excl)] = tid;
}

// ---------- gather compacted rows, fp32 -> bf16 ----------
__global__ __launch_bounds__(256) void k_gather(const float* __restrict__ xn, const int* __restrict__ aidx,
    const int* __restrict__ sidx, u16* __restrict__ xat, u16* __restrict__ xst)
{
  int id = blockIdx.x;
  int b = id >> 10, s = id & 1023;
  int src; u16* dst;
  if (s < 256) { src = aidx[b*256 + s]; dst = xat + (size_t)(b*256 + s)*1024; }
  else { int ss = s - 256; src = sidx[b*768 + ss]; dst = xst + (size_t)(b*768 + ss)*1024; }
  const float4* sp = (const float4*)(xn + ((size_t)b*1024 + src)*1024);
  int tid = threadIdx.x;
  float4 vv = sp[tid];
  union { u16 u[4]; uint2 d; } pk;
  pk.u[0]=f2b(vv.x); pk.u[1]=f2b(vv.y); pk.u[2]=f2b(vv.z); pk.u[3]=f2b(vv.w);
  ((uint2*)dst)[tid] = pk.d;
}

// ---------- MFMA bf16 GEMM, 2-phase pipelined, swizzled LDS ----------
// act: 0=none, 1=softplus, 2=gelu, 3=router (epilogue computes per-row partial
// of gelu(acc+bias)*w2 over this block's cols; outf=ps[16][M] indexed by
// blockIdx.y*2+wn, outb=(w2 ptr)).
template<int BM, int BN>
__global__ __launch_bounds__(256) void k_mfma(const u16* __restrict__ A, int lda,
    const u16* __restrict__ Bt, int ldb, const float* __restrict__ bias,
    float* __restrict__ outf, u16* __restrict__ outb, int M, int N, int K,
    int act, int split)
{
  constexpr int WTM = BM/2, WTN = BN/2;
  constexpr int MI = WTM/16, NJ = WTN/16;
  __shared__ u16 lA[2][BM*32];
  __shared__ u16 lB[2][BN*32];
  const int tid = threadIdx.x;
  const int lane = tid & 63;
  const int wv = tid >> 6;
  const int wm = wv >> 1, wn = wv & 1;
  const int tm = blockIdx.x * BM, tn = blockIdx.y * BN;
  const int r0 = lane & 15;
  const int kg = lane >> 4;

  const int ksl = K / gridDim.z;
  const int kbeg = blockIdx.z * ksl;
  if (gridDim.z > 1) outf += (size_t)blockIdx.z * ((size_t)M * N);

  auto stage = [&](int buf, int kt){
    for (int c = tid; c < BM*4; c += 256) {
      int row = c >> 2, j = c & 3;
      int jj = j ^ ((row >> 1) & 3);
      gload_lds16(&A[(size_t)(tm + row)*lda + kt + jj*8], &lA[buf][c*8]);
    }
    for (int c = tid; c < BN*4; c += 256) {
      int row = c >> 2, j = c & 3;
      int jj = j ^ ((row >> 1) & 3);
      gload_lds16(&Bt[(size_t)(tn + row)*ldb + kt + jj*8], &lB[buf][c*8]);
    }
  };

  f32x4 acc[MI][NJ];
  #pragma unroll
  for (int i=0;i<MI;i++)
    #pragma unroll
    for (int j=0;j<NJ;j++) acc[i][j] = (f32x4){0.f,0.f,0.f,0.f};

  stage(0, kbeg);
  __syncthreads();
  const int nk = ksl / 32;
  int cur = 0;
  for (int t = 0; t < nk; t++) {
    if (t + 1 < nk) stage(cur ^ 1, kbeg + (t+1)*32);
    short8 av[MI], bvv[NJ];
    #pragma unroll
    for (int i=0;i<MI;i++){
      int row = wm*WTM + i*16 + r0;
      av[i] = *(const short8*)&lA[cur][row*32 + ((kg ^ ((row>>1)&3))<<3)];
    }
    #pragma unroll
    for (int j=0;j<NJ;j++){
      int row = wn*WTN + j*16 + r0;
      bvv[j] = *(const short8*)&lB[cur][row*32 + ((kg ^ ((row>>1)&3))<<3)];
    }
    #pragma unroll
    for (int i=0;i<MI;i++)
      #pragma unroll
      for (int j=0;j<NJ;j++)
        acc[i][j] = __builtin_amdgcn_mfma_f32_16x16x32_bf16(av[i], bvv[j], acc[i][j], 0, 0, 0);
    __syncthreads();
    cur ^= 1;
  }

  if (act == 3) {
    // router epilogue: per-row partial score over THIS WAVE's columns.
    // slot indexed by (blockIdx.y, wn) so the two wn-waves never collide.
    const float* w2 = (const float*)outb;
    #pragma unroll
    for (int i=0;i<MI;i++){
      #pragma unroll
      for (int r=0;r<4;r++){
        float t = 0.f;
        #pragma unroll
        for (int j=0;j<NJ;j++){
          int col = tn + wn*WTN + j*16 + r0;
          t += gelu_f(acc[i][j][r] + bias[col]) * w2[col];
        }
        #pragma unroll
        for (int o=1;o<16;o<<=1) t += __shfl_xor(t, o, 64);
        if (r0 == 0)
          outf[(size_t)(blockIdx.y*2 + wn)*M + tm + wm*WTM + i*16 + kg*4 + r] = t;
      }
    }
    return;
  }

  const int rr = kg * 4;
  #pragma unroll
  for (int i=0;i<MI;i++){
    #pragma unroll
    for (int j=0;j<NJ;j++){
      #pragma unroll
      for (int r=0;r<4;r++){
        int row = tm + wm*WTM + i*16 + rr + r;
        int col = tn + wn*WTN + j*16 + r0;
        float v = acc[i][j][r];
        if (bias) v += bias[col];
        if (act == 1) v = (v > 15.f) ? v : log1pf(__expf(v));
        else if (act == 2) v = gelu_f(v);
        if (col < split) outf[(size_t)row*split + col] = v;
        else             outb[(size_t)row*(N-split) + (col-split)] = f2b(v);
      }
    }
  }
}

// ---------- split-K partial reduction for x-proj (+ dtp bf16 extract) ----------
__global__ __launch_bounds__(256) void k_psum(const float* __restrict__ p, float* __restrict__ o,
    u16* __restrict__ dtpb)
{
  int i = blockIdx.x*256 + threadIdx.x;   // 3072*96 = 294912
  float v = p[i] + p[i+294912] + p[i+589824] + p[i+884736];
  o[i] = v;
  int tok = i / 96, col = i - tok*96;
  if (col < 64) dtpb[tok*64 + col] = f2b(v);
}

// ---------- MFMA attention core (qkv packed [tok][3072]: q|k|v) ----------
__global__ __launch_bounds__(256) void k_attn2(const u16* __restrict__ qkv, u16* __restrict__ ob)
{
  __shared__ u16 lKP[16384];
  __shared__ u16 lVt[16384];
  char* KP = (char*)lKP;
  char* VT = (char*)lVt;
  const int tid = threadIdx.x;
  const int lane = tid & 63;
  const int w = tid >> 6;
  const int bx = blockIdx.x;
  const int b = bx >> 6, h = (bx >> 2) & 15, ch = bx & 3;

  const u16* kbase = qkv + (size_t)(b*256)*3072 + 1024 + h*64;
  const u16* vbase = qkv + (size_t)(b*256)*3072 + 2048 + h*64;

  {
    int rr = tid >> 3;
    int c8 = (tid & 7) * 8;
    for (int i = 0; i < 8; i++) {
      int row = i*32 + rr;
      int4 kv = *(const int4*)&kbase[(size_t)row*3072 + c8];
      int koff = row*128 + c8*2;
      *(int4*)(KP + (koff ^ ((row & 7) << 4))) = kv;
      int4 vv = *(const int4*)&vbase[(size_t)row*3072 + c8];
      union { int4 q; u16 u[8]; } vu; vu.q = vv;
      #pragma unroll
      for (int jj = 0; jj < 8; jj++) {
        int j = (jj + rr) & 7;
        int d = c8 + j;
        int voff = d*512 + row*2;
        *(u16*)(VT + (voff ^ ((d & 7) << 4))) = vu.u[j];
      }
    }
  }

  const int r0 = lane & 15;
  const int kg = lane >> 4;
  const int qrow = ch*64 + w*16 + r0;
  const u16* qp = qkv + (size_t)(b*256 + qrow)*3072 + h*64 + kg*8;
  short8 qf0 = *(const short8*)(qp);
  short8 qf1 = *(const short8*)(qp + 32);

  __syncthreads();

  f32x4 acc[16];
  #pragma unroll
  for (int t = 0; t < 16; t++) acc[t] = (f32x4){0.f,0.f,0.f,0.f};
  #pragma unroll
  for (int t = 0; t < 16; t++) {
    int row = t*16 + r0;
    int base = row*128 + kg*16;
    short8 kf0 = *(const short8*)(KP + ((base     ) ^ ((row & 7) << 4)));
    short8 kf1 = *(const short8*)(KP + ((base + 64) ^ ((row & 7) << 4)));
    acc[t] = __builtin_amdgcn_mfma_f32_16x16x32_bf16(qf0, kf0, acc[t], 0, 0, 0);
    acc[t] = __builtin_amdgcn_mfma_f32_16x16x32_bf16(qf1, kf1, acc[t], 0, 0, 0);
  }

  #pragma unroll
  for (int t = 0; t < 16; t++) acc[t] = acc[t] * 0.125f;
  float lsum[4];
  #pragma unroll
  for (int r = 0; r < 4; r++) {
    float mx = -1e30f;
    #pragma unroll
    for (int t = 0; t < 16; t++) mx = fmaxf(mx, acc[t][r]);
    #pragma unroll
    for (int o = 1; o < 16; o <<= 1) mx = fmaxf(mx, __shfl_xor(mx, o, 64));
    float s = 0.f;
    #pragma unroll
    for (int t = 0; t < 16; t++) { float p = __expf(acc[t][r] - mx); acc[t][r] = p; s += p; }
    #pragma unroll
    for (int o = 1; o < 16; o <<= 1) s += __shfl_xor(s, o, 64);
    lsum[r] = s;
  }

  __syncthreads();
  char* PW = KP + w*8192;
  #pragma unroll
  for (int t = 0; t < 16; t++) {
    int col = t*16 + r0;
    #pragma unroll
    for (int r = 0; r < 4; r++) {
      int row = kg*4 + r;
      int off = row*512 + col*2;
      *(u16*)(PW + (off ^ ((row & 7) << 4))) = f2b(acc[t][r]);
    }
  }

  f32x4 oacc[4];
  #pragma unroll
  for (int dt = 0; dt < 4; dt++) oacc[dt] = (f32x4){0.f,0.f,0.f,0.f};
  #pragma unroll
  for (int kc = 0; kc < 8; kc++) {
    int pbase = r0*512 + kc*64 + kg*16;
    short8 pf = *(const short8*)(PW + (pbase ^ ((r0 & 7) << 4)));
    #pragma unroll
    for (int dt = 0; dt < 4; dt++) {
      int vrow = dt*16 + r0;
      int vb2 = vrow*512 + kc*64 + kg*16;
      short8 vf = *(const short8*)(VT + (vb2 ^ ((vrow & 7) << 4)));
      oacc[dt] = __builtin_amdgcn_mfma_f32_16x16x32_bf16(pf, vf, oacc[dt], 0, 0, 0);
    }
  }

  u16* op = ob + (size_t)(b*256 + ch*64 + w*16)*1024 + h*64;
  #pragma unroll
  for (int dt = 0; dt < 4; dt++) {
    #pragma unroll
    for (int r = 0; r < 4; r++) {
      int row = kg*4 + r;
      float v = oacc[dt][r] / lsum[r];
      op[(size_t)row*1024 + dt*16 + r0] = f2b(v);
    }
  }
}

// ---------- causal depthwise conv (DC=4) + SiLU ----------
__global__ __launch_bounds__(256) void k_conv(const float* __restrict__ xi, const float* __restrict__ cw,
    const float* __restrict__ cb, float* __restrict__ xc, u16* __restrict__ xcb)
{
  size_t idx = (size_t)blockIdx.x*256 + threadIdx.x;
  int d = (int)(idx & 2047);
  size_t bt = idx >> 11;
  int t = (int)(bt % 768);
  float acc = cb[d];
  const float* p = xi + idx;
  float w0=cw[d*4+0], w1=cw[d*4+1], w2=cw[d*4+2], w3=cw[d*4+3];
  acc += w3 * p[0];
  if (t >= 1) acc += w2 * p[-2048];
  if (t >= 2) acc += w1 * p[-4096];
  if (t >= 3) acc += w0 * p[-6144];
  float sv = acc / (1.f + __expf(-acc));
  xc[idx]  = sv;
  xcb[idx] = f2b(sv);
}

// ================= chunked parallel selective scan =================
__global__ __launch_bounds__(256) void k_scan1(const float* __restrict__ delta, const float* __restrict__ xc,
    const float* __restrict__ proj, const float* __restrict__ A_log, float* __restrict__ cs)
{
  int bid = blockIdx.x;
  int db = bid & 7;
  int c  = (bid >> 3) & 15;
  int b  = bid >> 7;
  int d  = db*256 + threadIdx.x;
  float Ar[16];
  #pragma unroll
  for (int s=0;s<16;s++) Ar[s] = -__expf(A_log[d*16+s]);
  float ap[16], hc[16];
  #pragma unroll
  for (int s=0;s<16;s++){ ap[s]=1.f; hc[s]=0.f; }
  size_t row0 = (size_t)b*768 + c*48;
  for (int t=0;t<48;t++){
    size_t row = row0 + t;
    float dl = delta[row*2048 + d];
    float xv = xc[row*2048 + d];
    float du = dl*xv;
    const float4* bp = (const float4*)&proj[row*96 + 64];
    float4 b0 = bp[0], b1 = bp[1], b2 = bp[2], b3 = bp[3];
    float Bc[16] = {b0.x,b0.y,b0.z,b0.w,b1.x,b1.y,b1.z,b1.w,
                    b2.x,b2.y,b2.z,b2.w,b3.x,b3.y,b3.z,b3.w};
    #pragma unroll
    for (int s=0;s<16;s++){
      float dA = __expf(dl*Ar[s]);
      ap[s] *= dA;
      hc[s] = dA*hc[s] + du*Bc[s];
    }
  }
  size_t base = ((size_t)(b*16 + c)*32)*2048 + d;
  #pragma unroll
  for (int s=0;s<16;s++){
    cs[base + (size_t)s*2048]      = ap[s];
    cs[base + (size_t)(16+s)*2048] = hc[s];
  }
}

__global__ __launch_bounds__(256) void k_scan2(float* __restrict__ cs)
{
  int bid = blockIdx.x;
  int db = bid & 7;
  int s  = (bid >> 3) & 15;
  int b  = bid >> 7;
  int d  = db*256 + threadIdx.x;
  float h = 0.f;
  for (int c=0;c<16;c++){
    size_t base = ((size_t)(b*16 + c)*32)*2048 + d;
    float ap = cs[base + (size_t)s*2048];
    float hc = cs[base + (size_t)(16+s)*2048];
    cs[base + (size_t)(16+s)*2048] = h;
    h = ap*h + hc;
  }
}

__global__ __launch_bounds__(256) void k_scan3(const float* __restrict__ delta, const float* __restrict__ xc,
    const float* __restrict__ proj, const float* __restrict__ cs, const u16* __restrict__ zb,
    const float* __restrict__ A_log, const float* __restrict__ Dp, u16* __restrict__ yb)
{
  int bid = blockIdx.x;
  int db = bid & 7;
  int c  = (bid >> 3) & 15;
  int b  = bid >> 7;
  int d  = db*256 + threadIdx.x;
  float Ar[16];
  #pragma unroll
  for (int s=0;s<16;s++) Ar[s] = -__expf(A_log[d*16+s]);
  float dpv = Dp[d];
  float h[16];
  size_t base = ((size_t)(b*16 + c)*32)*2048 + d;
  #pragma unroll
  for (int s=0;s<16;s++) h[s] = cs[base + (size_t)(16+s)*2048];
  size_t row0 = (size_t)b*768 + c*48;
  for (int t=0;t<48;t++){
    size_t row = row0 + t;
    float dl = delta[row*2048 + d];
    float xv = xc[row*2048 + d];
    float du = dl*xv;
    const float4* bp = (const float4*)&proj[row*96 + 64];
    float4 b0 = bp[0], b1 = bp[1], b2 = bp[2], b3 = bp[3];
    const float4* cp = (const float4*)&proj[row*96 + 80];
    float4 c0 = cp[0], c1 = cp[1], c2 = cp[2], c3 = cp[3];
    float Bc[16] = {b0.x,b0.y,b0.z,b0.w,b1.x,b1.y,b1.z,b1.w,
                    b2.x,b2.y,b2.z,b2.w,b3.x,b3.y,b3.z,b3.w};
    float Cc[16] = {c0.x,c0.y,c0.z,c0.w,c1.x,c1.y,c1.z,c1.w,
                    c2.x,c2.y,c2.z,c2.w,c3.x,c3.y,c3.z,c3.w};
    float y = 0.f;
    #pragma unroll
    for (int s=0;s<16;s++){
      float dA = __expf(dl*Ar[s]);
      h[s] = dA*h[s] + du*Bc[s];
      y += h[s]*Cc[s];
    }
    y += xv*dpv;
    float z = b2f(zb[row*2048 + d]);
    float g = z / (1.f + __expf(-z));
    yb[row*2048 + d] = f2b(y*g);
  }
}

// ---------- scatter (float4) ----------
__global__ __launch_bounds__(256) void k_scat(const float* __restrict__ x, const int* __restrict__ idxarr,
    const float* __restrict__ dlt, float* __restrict__ out, int per_b)
{
  int id = blockIdx.x;
  int b = id / per_b;
  int t = idxarr[id];
  const float4* xp = (const float4*)(x + ((size_t)b*1024 + t)*1024);
  const float4* dp = (const float4*)(dlt + (size_t)id*1024);
  float4* op = (float4*)(out + ((size_t)b*1024 + t)*1024);
  int tid = threadIdx.x;
  float4 a = xp[tid], d = dp[tid];
  op[tid] = (float4){a.x+d.x, a.y+d.y, a.z+d.z, a.w+d.w};
}

// ------------------------------------------------------------------
extern "C" void kernel_launch(void* const* d_in, const int* in_sizes, int n_in,
                              void* d_out, int out_size, void* d_ws, size_t ws_size,
                              hipStream_t stream)
{
  const float* x      = (const float*)d_in[0];
  const float* ln_w   = (const float*)d_in[1];
  const float* ln_b   = (const float*)d_in[2];
  const float* r_w1   = (const float*)d_in[3];
  const float* r_b1   = (const float*)d_in[4];
  const float* r_w2   = (const float*)d_in[5];
  const float* r_b2   = (const float*)d_in[6];
  const float* Wq     = (const float*)d_in[7];
  const float* bq     = (const float*)d_in[8];
  const float* Wk     = (const float*)d_in[9];
  const float* bk     = (const float*)d_in[10];
  const float* Wv     = (const float*)d_in[11];
  const float* bv     = (const float*)d_in[12];
  const float* Wo     = (const float*)d_in[13];
  const float* bo     = (const float*)d_in[14];
  const float* in_w   = (const float*)d_in[15];
  const float* conv_w = (const float*)d_in[16];
  const float* conv_b = (const float*)d_in[17];
  const float* xproj_w= (const float*)d_in[18];
  const float* dt_w   = (const float*)d_in[19];
  const float* dt_b   = (const float*)d_in[20];
  const float* A_log  = (const float*)d_in[21];
  const float* Dp     = (const float*)d_in[22];
  const float* out_w  = (const float*)d_in[23];
  float* out = (float*)d_out;

  uint8_t* ws = (uint8_t*)d_ws;
  size_t off = 0;
  auto alloc = [&](size_t bytes)->uint8_t*{
    uint8_t* p = ws + off;
    off += (bytes + 255) & ~(size_t)255;
    return p;
  };

  float* xn    = (float*)alloc(4096ull*1024*4);
  u16*   wqt   = (u16*)  alloc(1024ull*1024*2);   // wqt/wkt/wvt contiguous => [3072][1024]
  u16*   wkt   = (u16*)  alloc(1024ull*1024*2);
  u16*   wvt   = (u16*)  alloc(1024ull*1024*2);
  u16*   wot   = (u16*)  alloc(1024ull*1024*2);
  u16*   inwt  = (u16*)  alloc(4096ull*1024*2);
  u16*   outwt = (u16*)  alloc(1024ull*2048*2);
  u16*   xpwt  = (u16*)  alloc(96ull*2048*2);
  u16*   dtwt  = (u16*)  alloc(2048ull*64*2);
  u16*   r1pk  = (u16*)  alloc(512ull*3072*2);    // router B_packed
  float* scores= (float*)alloc(4096*4);
  int*   aidx  = (int*)  alloc(1024*4);
  int*   sidx  = (int*)  alloc(3072*4);
  u16*   xat   = (u16*)  alloc(1024ull*1024*2);
  u16*   xst   = (u16*)  alloc(3072ull*1024*2);
  float* qkvb  = (float*)alloc(3072*4);

  // xn region reuse: split-K partials (before scan), then scan chunk-state (16MB)
  float* s_projp = xn;
  float* cs = xn;

  uint8_t* arena = ws + off;
  // phase: router
  u16*   apk = (u16*)(arena);                                 // A_packed 4096*3072*2 = 25.2 MB
  float* ps  = (float*)(arena + 25165824);                    // score partials 16*4096*4 = 256 KB
  // phase: attention
  u16*   qkvbuf = (u16*)(arena);                              // 6 MB
  u16*   obuf   = (u16*)(arena + 6291456);                    // 2 MB
  float* adelta = (float*)(arena + 8388608);                  // 4 MB
  // phase: ssm
  float* s_xi   = (float*)(arena);                            // 25165824 (reused as delta)
  u16*   s_zb   = (u16*)(arena + 25165824);                   // 12582912 (reused as ssm_delta fp32)
  float* s_xc   = (float*)(arena + 37748736);                 // 25165824
  u16*   s_xcb  = (u16*)(arena + 62914560);                   // 12582912 (reused as y bf16)
  float* s_proj = (float*)(arena + 75497472);                 // 1179648
  u16*   s_dtpb = (u16*)(arena + 76677120);                   // 393216
  float* s_delta  = s_xi;
  u16*   s_yb     = s_xcb;
  float* s_sdelta = (float*)s_zb;

  // 1) LayerNorm
  hipLaunchKernelGGL(k_ln, dim3(4096), dim3(256), 0, stream, x, ln_w, ln_b, xn);
  // 2) weight convert+transpose to bf16 [N][K] + bias pack + router splits
  hipLaunchKernelGGL(k_tcvt, dim3(32,32),  dim3(256), 0, stream, Wq,     wqt,   1024, 1024);
  hipLaunchKernelGGL(k_tcvt, dim3(32,32),  dim3(256), 0, stream, Wk,     wkt,   1024, 1024);
  hipLaunchKernelGGL(k_tcvt, dim3(32,32),  dim3(256), 0, stream, Wv,     wvt,   1024, 1024);
  hipLaunchKernelGGL(k_tcvt, dim3(32,32),  dim3(256), 0, stream, Wo,     wot,   1024, 1024);
  hipLaunchKernelGGL(k_tcvt, dim3(128,32), dim3(256), 0, stream, in_w,   inwt,  1024, 4096);
  hipLaunchKernelGGL(k_tcvt, dim3(32,64),  dim3(256), 0, stream, out_w,  outwt, 2048, 1024);
  hipLaunchKernelGGL(k_tcvt, dim3(3,64),   dim3(256), 0, stream, xproj_w,xpwt,  2048, 96);
  hipLaunchKernelGGL(k_tcvt, dim3(64,2),   dim3(256), 0, stream, dt_w,   dtwt,  64,   2048);
  hipLaunchKernelGGL(k_bpack, dim3(12), dim3(256), 0, stream, bq, bk, bv, qkvb);
  hipLaunchKernelGGL(k_splitB, dim3(16,32), dim3(256), 0, stream, r_w1, r1pk);
  hipLaunchKernelGGL(k_splitA, dim3(4096), dim3(256), 0, stream, xn, apk);
  // 3) router GEMM (split-bf16 MFMA, K=3072) with fused gelu+w2 partial-score epilogue
  hipLaunchKernelGGL((k_mfma<64,64>), dim3(64,8), dim3(256), 0, stream,
      apk, 3072, r1pk, 3072, r_b1, ps, (u16*)r_w2, 4096, 512, 3072, 3, 0);
  // 4) score reduce
  hipLaunchKernelGGL(k_score3, dim3(16), dim3(256), 0, stream, ps, r_b2, scores);
  // 5) top-k + compaction
  hipLaunchKernelGGL(k_topk, dim3(4), dim3(1024), 0, stream, scores, aidx, sidx);
  // 6) gather
  hipLaunchKernelGGL(k_gather, dim3(4096), dim3(256), 0, stream, xn, aidx, sidx, xat, xst);
  // 7) QKV merged (N=3072, bf16 out)
  hipLaunchKernelGGL((k_mfma<32,128>), dim3(32,24), dim3(256), 0, stream,
      xat, 1024, wqt, 1024, qkvb, (float*)nullptr, qkvbuf, 1024, 3072, 1024, 0, 0);
  // 8) attention core (MFMA)
  hipLaunchKernelGGL(k_attn2, dim3(256), dim3(256), 0, stream, qkvbuf, obuf);
  // 9) Wo projection (fp32 out)
  hipLaunchKernelGGL((k_mfma<32,64>), dim3(32,16), dim3(256), 0, stream,
      obuf, 1024, wot, 1024, bo, adelta, (u16*)nullptr, 1024, 1024, 1024, 0, 1024);
  // 10) scatter attention tokens
  hipLaunchKernelGGL(k_scat, dim3(1024), dim3(256), 0, stream, x, aidx, adelta, out, 256);
  // 11) SSM in-proj merged: xi (fp32, cols<2048) + z (bf16, cols>=2048)
  hipLaunchKernelGGL((k_mfma<128,128>), dim3(24,32), dim3(256), 0, stream,
      xst, 1024, inwt, 1024, (const float*)nullptr, s_xi, s_zb, 3072, 4096, 1024, 0, 2048);
  // 12) conv + silu
  hipLaunchKernelGGL(k_conv, dim3(24576), dim3(256), 0, stream, s_xi, conv_w, conv_b, s_xc, s_xcb);
  // 13) x-proj, split-K=4 (partials in xn region) + reduce (+dtp extract)
  hipLaunchKernelGGL((k_mfma<32,96>), dim3(96,1,4), dim3(256), 0, stream,
      s_xcb, 2048, xpwt, 2048, (const float*)nullptr, s_projp, (u16*)nullptr, 3072, 96, 2048, 0, 96);
  hipLaunchKernelGGL(k_psum, dim3(1152), dim3(256), 0, stream, s_projp, s_proj, s_dtpb);
  // 15) dt GEMM + softplus -> delta
  hipLaunchKernelGGL((k_mfma<64,128>), dim3(48,16), dim3(256), 0, stream,
      s_dtpb, 64, dtwt, 64, dt_b, s_delta, (u16*)nullptr, 3072, 2048, 64, 1, 2048);
  // 16) chunked parallel scan (3 phases) + gating -> y bf16
  hipLaunchKernelGGL(k_scan1, dim3(512), dim3(256), 0, stream, s_delta, s_xc, s_proj, A_log, cs);
  hipLaunchKernelGGL(k_scan2, dim3(512), dim3(256), 0, stream, cs);
  hipLaunchKernelGGL(k_scan3, dim3(512), dim3(256), 0, stream, s_delta, s_xc, s_proj, cs, s_zb, A_log, Dp, s_yb);
  // 17) out-proj
  hipLaunchKernelGGL((k_mfma<32,128>), dim3(96,8), dim3(256), 0, stream,
      s_yb, 2048, outwt, 2048, (const float*)nullptr, s_sdelta, (u16*)nullptr, 3072, 1024, 2048, 0, 1024);
  // 18) scatter ssm tokens
  hipLaunchKernelGGL(k_scat, dim3(3072), dim3(256), 0, stream, x, sidx, s_sdelta, out, 768);
}